// Round 3
// baseline (2195.808 us; speedup 1.0000x reference)
//
#include <hip/hip_runtime.h>
#include <hip/hip_bf16.h>
#include <math.h>

typedef __hip_bfloat16 bf16;
typedef __attribute__((ext_vector_type(8))) short short8;
typedef __attribute__((ext_vector_type(4))) float floatx4;

#define NEG_MAX 3.402823466e38f

// ---------- helpers ----------
__device__ __forceinline__ void gload16(const void* g, void* l) {
  __builtin_amdgcn_global_load_lds(
      (const __attribute__((address_space(1))) unsigned int*)g,
      (__attribute__((address_space(3))) unsigned int*)l, 16, 0, 0);
}
__device__ __forceinline__ floatx4 mfma_bf16(short8 a, short8 b, floatx4 c) {
  return __builtin_amdgcn_mfma_f32_16x16x32_bf16(a, b, c, 0, 0, 0);
}

// ---------- weight prep: f32 (K,N) -> bf16 (pN,pK) transposed, zero-pad ----------
// mode 0: plain; mode 1: w_ff1 a/g split (srcN=2730 -> pN=2816: rows 0..1364 = cols
// 0..1364 (a), rows 1408..2772 = cols 1365..2729 (g))
__global__ __launch_bounds__(256) void prep_w(const float* __restrict__ src,
                                              bf16* __restrict__ dst,
                                              int K, int N, int pK, int pN, int nl, int mode) {
  int idx = blockIdx.x * 256 + threadIdx.x;
  long total = (long)nl * pN * pK;
  if (idx >= total) return;
  int l = idx / (pN * pK);
  int r = idx % (pN * pK);
  int n = r / pK, k = r % pK;
  const float* s = src + (size_t)l * K * N;
  float v = 0.f;
  if (k < K) {
    int sc = -1;
    if (mode == 0) { if (n < N) sc = n; }
    else { if (n < 1365) sc = n; else if (n >= 1408 && n < 2773) sc = 1365 + (n - 1408); }
    if (sc >= 0) v = s[(size_t)k * N + sc];
  }
  dst[idx] = __float2bfloat16(v);
}

// ---------- dynamic position bias table: tab[256][8] f32 ----------
__global__ __launch_bounds__(256) void dpb_kernel(const float* w1, const float* b1,
                                                  const float* w2, const float* b2,
                                                  const float* w3, const float* b3,
                                                  float* __restrict__ tab) {
  __shared__ float h1[256];
  __shared__ float h2s[256];
  int t = blockIdx.x, e = threadIdx.x;
  float rel = (float)t;
  float a = rel * w1[e] + b1[e];
  h1[e] = a / (1.f + expf(-a));           // silu
  __syncthreads();
  float s = b2[e];
  for (int d = 0; d < 256; d++) s += h1[d] * w2[d * 256 + e];
  h2s[e] = s / (1.f + expf(-s));
  __syncthreads();
  if (e < 8) {
    float s2 = b3[e];
    for (int d = 0; d < 256; d++) s2 += h2s[d] * w3[d * 8 + e];
    tab[t * 8 + e] = s2;
  }
}

// ---------- embedding + sinusoidal pos emb -> f32 residual stream ----------
__global__ __launch_bounds__(256) void embed_kernel(const int* __restrict__ x,
                                                    const float* __restrict__ emb,
                                                    float* __restrict__ h) {
  int idx = blockIdx.x * 256 + threadIdx.x;   // over 16384*512
  int bn = idx >> 9, d = idx & 511;
  int n = bn & 2047;
  int xv = x[bn];
  float e = (xv != 0) ? emb[(size_t)xv * 512 + d] : 0.f;
  int k = d & 255;
  float inv = powf(10000.f, -(float)k * (1.f / 256.f));
  float s = (float)n * inv;
  float pe = (d < 256) ? sinf(s) : cosf(s);
  h[idx] = e + pe;
}

// ---------- LayerNorm (f32 in, bf16 out), one wave per row ----------
__global__ __launch_bounds__(256) void ln_kernel(const float* __restrict__ h,
                                                 const float* __restrict__ g,
                                                 const float* __restrict__ b,
                                                 bf16* __restrict__ z) {
  int wv = threadIdx.x >> 6, lane = threadIdx.x & 63;
  size_t row = (size_t)blockIdx.x * 4 + wv;
  const float* xr = h + row * 512;
  float v[8];
  float s = 0.f;
#pragma unroll
  for (int i = 0; i < 8; i++) { v[i] = xr[lane * 8 + i]; s += v[i]; }
#pragma unroll
  for (int o = 32; o > 0; o >>= 1) s += __shfl_xor(s, o);
  float mean = s * (1.f / 512.f);
  float q = 0.f;
#pragma unroll
  for (int i = 0; i < 8; i++) { float d = v[i] - mean; q += d * d; }
#pragma unroll
  for (int o = 32; o > 0; o >>= 1) q += __shfl_xor(q, o);
  float rs = rsqrtf(q * (1.f / 512.f) + 1e-5f);
  bf16* zr = z + row * 512;
#pragma unroll
  for (int i = 0; i < 8; i++) {
    int col = lane * 8 + i;
    float o2 = (v[i] - mean) * rs * g[col] + b[col];
    zr[col] = __float2bfloat16(o2);
  }
}

// ---------- GEMM: C(M,N) = A(M,K)bf16 @ BT(N,K)bf16; 128x128 tile, BK=64 ----------
// EPI 0: bf16 store. EPI 1: f32 residual add. EPI 2: fused GEGLU in-place
// (Cb[idx] = bf16(a_prev * gelu(acc))). EPI 3: f32 store.
template <int EPI>
__global__ __launch_bounds__(256, 2) void gemm_kernel(const bf16* __restrict__ A,
                                                      const bf16* __restrict__ BT,
                                                      bf16* __restrict__ Cb,
                                                      float* __restrict__ Cf,
                                                      int Nsz, int Ksz) {
  __shared__ __align__(16) char smem[32768];   // A tile [128][128B] @0, B tile @16384
  const int tid = threadIdx.x, wv = tid >> 6, lane = tid & 63;
  const int lr = lane & 15, lg = lane >> 4;
  const int m0 = blockIdx.y * 128, n0 = blockIdx.x * 128;
  const int wm = (wv >> 1) * 64, wn = (wv & 1) * 64;
  const size_t Kb = (size_t)Ksz * 2;

  floatx4 acc[4][4];
#pragma unroll
  for (int i = 0; i < 4; i++)
#pragma unroll
    for (int j = 0; j < 4; j++)
#pragma unroll
      for (int r = 0; r < 4; r++) acc[i][j][r] = 0.f;

  for (int kt = 0; kt < Ksz; kt += 64) {
#pragma unroll
    for (int i = 0; i < 4; i++) {
      int off = i * 4096 + wv * 1024 + lane * 16;
      int row = off >> 7, colb = off & 127;
      int scol = colb ^ ((row & 7) << 4);
      gload16((const char*)A + (size_t)(m0 + row) * Kb + (size_t)kt * 2 + scol, smem + off);
    }
#pragma unroll
    for (int i = 0; i < 4; i++) {
      int off = i * 4096 + wv * 1024 + lane * 16;
      int row = off >> 7, colb = off & 127;
      int scol = colb ^ ((row & 7) << 4);
      gload16((const char*)BT + (size_t)(n0 + row) * Kb + (size_t)kt * 2 + scol,
              smem + 16384 + off);
    }
    __syncthreads();
#pragma unroll
    for (int kk = 0; kk < 64; kk += 32) {
      int kb = kk * 2 + lg * 16;
      short8 af[4], bfr[4];
#pragma unroll
      for (int mf = 0; mf < 4; mf++) {
        int row = wm + mf * 16 + lr;
        af[mf] = *(const short8*)(smem + row * 128 + (kb ^ ((row & 7) << 4)));
      }
#pragma unroll
      for (int nf = 0; nf < 4; nf++) {
        int row = wn + nf * 16 + lr;
        bfr[nf] = *(const short8*)(smem + 16384 + row * 128 + (kb ^ ((row & 7) << 4)));
      }
#pragma unroll
      for (int mf = 0; mf < 4; mf++)
#pragma unroll
        for (int nf = 0; nf < 4; nf++) acc[mf][nf] = mfma_bf16(af[mf], bfr[nf], acc[mf][nf]);
    }
    __syncthreads();
  }
#pragma unroll
  for (int mf = 0; mf < 4; mf++)
#pragma unroll
    for (int nf = 0; nf < 4; nf++)
#pragma unroll
      for (int r = 0; r < 4; r++) {
        int row = m0 + wm + mf * 16 + lg * 4 + r;
        int col = n0 + wn + nf * 16 + lr;
        float v = acc[mf][nf][r];
        size_t idx = (size_t)row * Nsz + col;
        if (EPI == 0) {
          Cb[idx] = __float2bfloat16(v);
        } else if (EPI == 1) {
          Cf[idx] += v;
        } else if (EPI == 2) {
          float a = __bfloat162float(Cb[idx]);
          float ge = 0.5f * v * (1.f + erff(v * 0.70710678118654752f));
          Cb[idx] = __float2bfloat16(a * ge);
        } else {
          Cf[idx] = v;
        }
      }
}

// ---------- local windowed attention; one block per (b, head, q-halfwindow) ----------
// QBLK=64 queries, 256 keys (prev+cur window). Q/K MFMA fragments read directly
// from global (row-contiguous, L2-resident). LDS (64KB exactly):
//   phase 1: km [0,1024) f32 | tabh [1024,2048) f32 | VT [32768,65536) 64x512B
//   phase 2 (after barrier): P [0,32768) 64x512B overlays km/tabh
// bf16 tiles XOR-swizzled by ((row&7)<<4) on the byte column.
__global__ __launch_bounds__(256) void attn_kernel(const bf16* __restrict__ qkv,
                                                   const int* __restrict__ x,
                                                   const float* __restrict__ tab,
                                                   bf16* __restrict__ ob) {
  __shared__ __align__(16) char smem[65536];
  float* km = (float*)smem;
  float* tabh = (float*)(smem + 1024);
  const int w2 = blockIdx.x, hh = blockIdx.y, b = blockIdx.z;
  const int w = w2 >> 1, qh = (w2 & 1) * 64;   // window, q-offset within window
  const int tid = threadIdx.x, wv = tid >> 6, lane = tid & 63;
  const int lr = lane & 15, lg = lane >> 4;
  const size_t qrow0 = (size_t)b * 2048 + (size_t)w * 128;   // first row of cur window

  // ---- stage V transposed VT[d][j] (64 rows x 512B), bias row, key mask ----
  for (int c = tid; c < 2048; c += 256) {
    int j = c >> 3, d0 = (c & 7) * 8;
    short8 vv;
    if (w == 0 && j < 128) {
#pragma unroll
      for (int t2 = 0; t2 < 8; t2++) vv[t2] = (short)0xBF80;   // pad V = -1.0
    } else {
      size_t gj = qrow0 + j - 128;
      vv = *(const short8*)(qkv + gj * 1536 + 1024 + hh * 64 + d0);
    }
#pragma unroll
    for (int t2 = 0; t2 < 8; t2++) {
      int d = d0 + t2;
      *(unsigned short*)(smem + 32768 + d * 512 + ((j * 2) ^ ((d & 7) << 4))) =
          (unsigned short)vv[t2];
    }
  }
  {
    tabh[tid] = tab[tid * 8 + hh];
    int j = tid;
    float kmv;
    if (w == 0 && j < 128) kmv = 0.f;                    // pad keys invalid
    else kmv = (x[qrow0 + j - 128] != 0) ? 1.f : 0.f;    // padding-token mask
    km[j] = kmv;
  }
  __syncthreads();

  // ---- sim = Q @ K^T : wave wv handles q rows wv*16..+16, all 256 keys ----
  floatx4 sim[16];
#pragma unroll
  for (int nf = 0; nf < 16; nf++)
#pragma unroll
    for (int r = 0; r < 4; r++) sim[nf][r] = 0.f;
#pragma unroll
  for (int kk = 0; kk < 64; kk += 32) {
    size_t qr = qrow0 + qh + wv * 16 + lr;
    short8 aq = *(const short8*)(qkv + qr * 1536 + hh * 64 + kk + lg * 8);
#pragma unroll
    for (int nf = 0; nf < 16; nf++) {
      int j = nf * 16 + lr;
      size_t gj = (w == 0 && j < 128) ? qrow0 : (qrow0 + j - 128);  // clamp: masked anyway
      short8 bk = *(const short8*)(qkv + gj * 1536 + 512 + hh * 64 + kk + lg * 8);
      sim[nf] = mfma_bf16(aq, bk, sim[nf]);
    }
  }
  // ---- scale + bias + mask + row softmax (16-lane groups over lr) ----
  float inv_s[4];
#pragma unroll
  for (int r = 0; r < 4; r++) {
    int qi = qh + wv * 16 + lg * 4 + r;   // q position within window, 0..127
    float mmax = -NEG_MAX;
#pragma unroll
    for (int nf = 0; nf < 16; nf++) {
      int j = nf * 16 + lr;
      int di = 128 + qi - j;
      if (di < 0) di = -di;
      float val = sim[nf][r] * 0.125f + tabh[di];
      bool valid = ((j < 128) ? (qi <= j) : (j - 128 <= qi)) && (km[j] > 0.5f);
      float mv = valid ? val : -NEG_MAX;
      sim[nf][r] = mv;
      mmax = fmaxf(mmax, mv);
    }
#pragma unroll
    for (int o = 8; o > 0; o >>= 1) mmax = fmaxf(mmax, __shfl_xor(mmax, o));
    float s = 0.f;
#pragma unroll
    for (int nf = 0; nf < 16; nf++) {
      float e = expf(sim[nf][r] - mmax);
      sim[nf][r] = e;
      s += e;
    }
#pragma unroll
    for (int o = 8; o > 0; o >>= 1) s += __shfl_xor(s, o);
    inv_s[r] = 1.f / s;
  }
  __syncthreads();   // km/tabh dead; safe to overlay P
  // ---- write P[64][512B] bf16 (swizzled) ----
#pragma unroll
  for (int nf = 0; nf < 16; nf++)
#pragma unroll
    for (int r = 0; r < 4; r++) {
      int qi = wv * 16 + lg * 4 + r;   // local row 0..63
      int j = nf * 16 + lr;
      *(unsigned short*)(smem + qi * 512 + ((j * 2) ^ ((qi & 7) << 4))) =
          __bfloat16_as_ushort(__float2bfloat16(sim[nf][r] * inv_s[r]));
    }
  __syncthreads();
  // ---- O = P @ V : wave wv rows wv*16..+16, cols 0..63 ----
  floatx4 oacc[4];
#pragma unroll
  for (int nf = 0; nf < 4; nf++)
#pragma unroll
    for (int r = 0; r < 4; r++) oacc[nf][r] = 0.f;
#pragma unroll
  for (int kk = 0; kk < 256; kk += 32) {
    int kb = kk * 2 + lg * 16;
    int row = wv * 16 + lr;
    short8 pa = *(const short8*)(smem + row * 512 + (kb ^ ((row & 7) << 4)));
#pragma unroll
    for (int nf = 0; nf < 4; nf++) {
      int d = nf * 16 + lr;
      short8 bv = *(const short8*)(smem + 32768 + d * 512 + (kb ^ ((d & 7) << 4)));
      oacc[nf] = mfma_bf16(pa, bv, oacc[nf]);
    }
  }
#pragma unroll
  for (int nf = 0; nf < 4; nf++)
#pragma unroll
    for (int r = 0; r < 4; r++) {
      size_t n = qrow0 + qh + wv * 16 + lg * 4 + r;
      ob[n * 512 + hh * 64 + nf * 16 + lr] = __float2bfloat16(oacc[nf][r]);
    }
}

// ---------- host launcher ----------
extern "C" void kernel_launch(void* const* d_in, const int* in_sizes, int n_in,
                              void* d_out, int out_size, void* d_ws, size_t ws_size,
                              hipStream_t stream) {
  const int* x = (const int*)d_in[0];
  const float* emb = (const float*)d_in[1];
  const float* lag = (const float*)d_in[2];
  const float* lab = (const float*)d_in[3];
  const float* wqkv = (const float*)d_in[4];
  const float* wout = (const float*)d_in[5];
  const float* lfg = (const float*)d_in[6];
  const float* lfb = (const float*)d_in[7];
  const float* wff1 = (const float*)d_in[8];
  const float* wff2 = (const float*)d_in[9];
  const float* dw1 = (const float*)d_in[10];
  const float* db1 = (const float*)d_in[11];
  const float* dw2 = (const float*)d_in[12];
  const float* db2 = (const float*)d_in[13];
  const float* dw3 = (const float*)d_in[14];
  const float* db3 = (const float*)d_in[15];
  const float* log_g = (const float*)d_in[16];
  const float* log_b = (const float*)d_in[17];
  const float* wlog = (const float*)d_in[18];

  // ws layout (~140 MB; ob aliases z; FF a/gelu buffer aliases qkv in `big`)
  char* ws = (char*)d_ws;
  size_t off = 0;
  float* h = (float*)(ws + off); off += (size_t)16384 * 512 * 4;        //  33.6 MB
  bf16* z = (bf16*)(ws + off); off += (size_t)16384 * 512 * 2;          //  16.8 MB
  bf16* ob = z;                                                          //  alias
  bf16* big = (bf16*)(ws + off); off += (size_t)16384 * 1536 * 2;       //  50.3 MB
  bf16* qkvT = (bf16*)(ws + off); off += (size_t)6 * 1536 * 512 * 2;    //   9.4 MB
  bf16* woutT = (bf16*)(ws + off); off += (size_t)6 * 512 * 512 * 2;    //   3.1 MB
  bf16* ff1T = (bf16*)(ws + off); off += (size_t)6 * 2816 * 512 * 2;    //  17.3 MB
  bf16* ff2T = (bf16*)(ws + off); off += (size_t)6 * 512 * 1408 * 2;    //   8.7 MB
  bf16* logT = (bf16*)(ws + off); off += (size_t)512 * 512 * 2;         //   0.5 MB
  float* tab = (float*)(ws + off); off += (size_t)256 * 8 * 4;          //   8 KB

  auto cdiv = [](long t) { return (int)((t + 255) / 256); };

  prep_w<<<cdiv(6L * 1536 * 512), 256, 0, stream>>>(wqkv, qkvT, 512, 1536, 512, 1536, 6, 0);
  prep_w<<<cdiv(6L * 512 * 512), 256, 0, stream>>>(wout, woutT, 512, 512, 512, 512, 6, 0);
  prep_w<<<cdiv(6L * 2816 * 512), 256, 0, stream>>>(wff1, ff1T, 512, 2730, 512, 2816, 6, 1);
  prep_w<<<cdiv(6L * 512 * 1408), 256, 0, stream>>>(wff2, ff2T, 1365, 512, 1408, 512, 6, 0);
  prep_w<<<cdiv(512L * 512), 256, 0, stream>>>(wlog, logT, 512, 512, 512, 512, 1, 0);
  dpb_kernel<<<256, 256, 0, stream>>>(dw1, db1, dw2, db2, dw3, db3, tab);
  embed_kernel<<<32768, 256, 0, stream>>>(x, emb, h);

  for (int l = 0; l < 6; l++) {
    ln_kernel<<<4096, 256, 0, stream>>>(h, lag + l * 512, lab + l * 512, z);
    gemm_kernel<0><<<dim3(12, 128), 256, 0, stream>>>(z, qkvT + (size_t)l * 1536 * 512,
                                                      big, nullptr, 1536, 512);
    attn_kernel<<<dim3(32, 8, 8), 256, 0, stream>>>(big, x, tab, ob);
    gemm_kernel<1><<<dim3(4, 128), 256, 0, stream>>>(ob, woutT + (size_t)l * 512 * 512,
                                                     nullptr, h, 512, 512);
    ln_kernel<<<4096, 256, 0, stream>>>(h, lfg + l * 512, lfb + l * 512, z);
    // FF: a-half then g-half with fused GEGLU epilogue (in-place over `big`)
    gemm_kernel<0><<<dim3(11, 128), 256, 0, stream>>>(z, ff1T + (size_t)l * 2816 * 512,
                                                      big, nullptr, 1408, 512);
    gemm_kernel<2><<<dim3(11, 128), 256, 0, stream>>>(
        z, ff1T + (size_t)l * 2816 * 512 + (size_t)1408 * 512, big, nullptr, 1408, 512);
    gemm_kernel<1><<<dim3(4, 128), 256, 0, stream>>>(big, ff2T + (size_t)l * 512 * 1408,
                                                     nullptr, h, 512, 1408);
  }
  ln_kernel<<<4096, 256, 0, stream>>>(h, log_g, log_b, z);
  gemm_kernel<3><<<dim3(4, 128), 256, 0, stream>>>(z, logT, nullptr, (float*)d_out, 512, 512);
}

// Round 4
// 2132.309 us; speedup vs baseline: 1.0298x; 1.0298x over previous
//
#include <hip/hip_runtime.h>
#include <hip/hip_bf16.h>
#include <math.h>

typedef __hip_bfloat16 bf16;
typedef __attribute__((ext_vector_type(8))) short short8;
typedef __attribute__((ext_vector_type(4))) float floatx4;

#define NEG_MAX 3.402823466e38f

// ---------- helpers ----------
__device__ __forceinline__ void gload16(const void* g, void* l) {
  __builtin_amdgcn_global_load_lds(
      (const __attribute__((address_space(1))) unsigned int*)g,
      (__attribute__((address_space(3))) unsigned int*)l, 16, 0, 0);
}
__device__ __forceinline__ floatx4 mfma_bf16(short8 a, short8 b, floatx4 c) {
  return __builtin_amdgcn_mfma_f32_16x16x32_bf16(a, b, c, 0, 0, 0);
}

// ---------- weight prep: f32 (K,N) -> bf16 (pN,pK) transposed, zero-pad ----------
// mode 0: plain; mode 1: w_ff1 a/g split (srcN=2730 -> pN=2816: rows 0..1364 = cols
// 0..1364 (a), rows 1408..2772 = cols 1365..2729 (g))
__global__ __launch_bounds__(256) void prep_w(const float* __restrict__ src,
                                              bf16* __restrict__ dst,
                                              int K, int N, int pK, int pN, int nl, int mode) {
  int idx = blockIdx.x * 256 + threadIdx.x;
  long total = (long)nl * pN * pK;
  if (idx >= total) return;
  int l = idx / (pN * pK);
  int r = idx % (pN * pK);
  int n = r / pK, k = r % pK;
  const float* s = src + (size_t)l * K * N;
  float v = 0.f;
  if (k < K) {
    int sc = -1;
    if (mode == 0) { if (n < N) sc = n; }
    else { if (n < 1365) sc = n; else if (n >= 1408 && n < 2773) sc = 1365 + (n - 1408); }
    if (sc >= 0) v = s[(size_t)k * N + sc];
  }
  dst[idx] = __float2bfloat16(v);
}

// ---------- dynamic position bias table: tab[256][8] f32 ----------
__global__ __launch_bounds__(256) void dpb_kernel(const float* w1, const float* b1,
                                                  const float* w2, const float* b2,
                                                  const float* w3, const float* b3,
                                                  float* __restrict__ tab) {
  __shared__ float h1[256];
  __shared__ float h2s[256];
  int t = blockIdx.x, e = threadIdx.x;
  float rel = (float)t;
  float a = rel * w1[e] + b1[e];
  h1[e] = a / (1.f + expf(-a));           // silu
  __syncthreads();
  float s = b2[e];
  for (int d = 0; d < 256; d++) s += h1[d] * w2[d * 256 + e];
  h2s[e] = s / (1.f + expf(-s));
  __syncthreads();
  if (e < 8) {
    float s2 = b3[e];
    for (int d = 0; d < 256; d++) s2 += h2s[d] * w3[d * 8 + e];
    tab[t * 8 + e] = s2;
  }
}

// ---------- embedding + sinusoidal pos emb -> f32 residual stream ----------
__global__ __launch_bounds__(256) void embed_kernel(const int* __restrict__ x,
                                                    const float* __restrict__ emb,
                                                    float* __restrict__ h) {
  int idx = blockIdx.x * 256 + threadIdx.x;   // over 16384*512
  int bn = idx >> 9, d = idx & 511;
  int n = bn & 2047;
  int xv = x[bn];
  float e = (xv != 0) ? emb[(size_t)xv * 512 + d] : 0.f;
  int k = d & 255;
  float inv = powf(10000.f, -(float)k * (1.f / 256.f));
  float s = (float)n * inv;
  float pe = (d < 256) ? sinf(s) : cosf(s);
  h[idx] = e + pe;
}

// ---------- LayerNorm (f32 in, bf16 out), one wave per row ----------
__global__ __launch_bounds__(256) void ln_kernel(const float* __restrict__ h,
                                                 const float* __restrict__ g,
                                                 const float* __restrict__ b,
                                                 bf16* __restrict__ z) {
  int wv = threadIdx.x >> 6, lane = threadIdx.x & 63;
  size_t row = (size_t)blockIdx.x * 4 + wv;
  const float* xr = h + row * 512;
  float v[8];
  float s = 0.f;
#pragma unroll
  for (int i = 0; i < 8; i++) { v[i] = xr[lane * 8 + i]; s += v[i]; }
#pragma unroll
  for (int o = 32; o > 0; o >>= 1) s += __shfl_xor(s, o);
  float mean = s * (1.f / 512.f);
  float q = 0.f;
#pragma unroll
  for (int i = 0; i < 8; i++) { float d = v[i] - mean; q += d * d; }
#pragma unroll
  for (int o = 32; o > 0; o >>= 1) q += __shfl_xor(q, o);
  float rs = rsqrtf(q * (1.f / 512.f) + 1e-5f);
  bf16* zr = z + row * 512;
#pragma unroll
  for (int i = 0; i < 8; i++) {
    int col = lane * 8 + i;
    float o2 = (v[i] - mean) * rs * g[col] + b[col];
    zr[col] = __float2bfloat16(o2);
  }
}

// ---------- GEMM: C(M,N) = A(M,K)bf16 @ BT(N,K)bf16; 128x128 tile, BK=64 ----------
// EPI 0: bf16 store. EPI 1: f32 residual add. EPI 2: fused GEGLU in-place
// (Cb[idx] = bf16(a_prev * gelu(acc))). EPI 3: f32 store.
template <int EPI>
__global__ __launch_bounds__(256, 2) void gemm_kernel(const bf16* __restrict__ A,
                                                      const bf16* __restrict__ BT,
                                                      bf16* __restrict__ Cb,
                                                      float* __restrict__ Cf,
                                                      int Nsz, int Ksz) {
  __shared__ __align__(16) char smem[32768];   // A tile [128][128B] @0, B tile @16384
  const int tid = threadIdx.x, wv = tid >> 6, lane = tid & 63;
  const int lr = lane & 15, lg = lane >> 4;
  const int m0 = blockIdx.y * 128, n0 = blockIdx.x * 128;
  const int wm = (wv >> 1) * 64, wn = (wv & 1) * 64;
  const size_t Kb = (size_t)Ksz * 2;

  floatx4 acc[4][4];
#pragma unroll
  for (int i = 0; i < 4; i++)
#pragma unroll
    for (int j = 0; j < 4; j++)
#pragma unroll
      for (int r = 0; r < 4; r++) acc[i][j][r] = 0.f;

  for (int kt = 0; kt < Ksz; kt += 64) {
#pragma unroll
    for (int i = 0; i < 4; i++) {
      int off = i * 4096 + wv * 1024 + lane * 16;
      int row = off >> 7, colb = off & 127;
      int scol = colb ^ ((row & 7) << 4);
      gload16((const char*)A + (size_t)(m0 + row) * Kb + (size_t)kt * 2 + scol, smem + off);
    }
#pragma unroll
    for (int i = 0; i < 4; i++) {
      int off = i * 4096 + wv * 1024 + lane * 16;
      int row = off >> 7, colb = off & 127;
      int scol = colb ^ ((row & 7) << 4);
      gload16((const char*)BT + (size_t)(n0 + row) * Kb + (size_t)kt * 2 + scol,
              smem + 16384 + off);
    }
    __syncthreads();
#pragma unroll
    for (int kk = 0; kk < 64; kk += 32) {
      int kb = kk * 2 + lg * 16;
      short8 af[4], bfr[4];
#pragma unroll
      for (int mf = 0; mf < 4; mf++) {
        int row = wm + mf * 16 + lr;
        af[mf] = *(const short8*)(smem + row * 128 + (kb ^ ((row & 7) << 4)));
      }
#pragma unroll
      for (int nf = 0; nf < 4; nf++) {
        int row = wn + nf * 16 + lr;
        bfr[nf] = *(const short8*)(smem + 16384 + row * 128 + (kb ^ ((row & 7) << 4)));
      }
#pragma unroll
      for (int mf = 0; mf < 4; mf++)
#pragma unroll
        for (int nf = 0; nf < 4; nf++) acc[mf][nf] = mfma_bf16(af[mf], bfr[nf], acc[mf][nf]);
    }
    __syncthreads();
  }
#pragma unroll
  for (int mf = 0; mf < 4; mf++)
#pragma unroll
    for (int nf = 0; nf < 4; nf++)
#pragma unroll
      for (int r = 0; r < 4; r++) {
        int row = m0 + wm + mf * 16 + lg * 4 + r;
        int col = n0 + wn + nf * 16 + lr;
        float v = acc[mf][nf][r];
        size_t idx = (size_t)row * Nsz + col;
        if (EPI == 0) {
          Cb[idx] = __float2bfloat16(v);
        } else if (EPI == 1) {
          Cf[idx] += v;
        } else if (EPI == 2) {
          float a = __bfloat162float(Cb[idx]);
          float ge = 0.5f * v * (1.f + erff(v * 0.70710678118654752f));
          Cb[idx] = __float2bfloat16(a * ge);
        } else {
          Cf[idx] = v;
        }
      }
}

// ---------- local windowed attention, swapped-QK in-register softmax ----------
// One block per (b, head, q-halfwindow): 64 q rows, 256 keys.
// sim = mfma(A=K, B=Q) -> D[j][q]: thread (lr,lg) holds q=lr, j = nf*16+lg*4+r
// -> softmax reduce = in-reg + 2 shuffles; P written as packed b64, 2 j-tiles.
// LDS (51200B): P [0,16384) 64x256B | VT [16384,49152) 64x512B
//               km @49152 (256 f32) | tabh @50176 (256 f32)
__global__ __launch_bounds__(256) void attn_kernel(const bf16* __restrict__ qkv,
                                                   const int* __restrict__ x,
                                                   const float* __restrict__ tab,
                                                   bf16* __restrict__ ob) {
  __shared__ __align__(16) char smem[51200];
  float* km = (float*)(smem + 49152);
  float* tabh = (float*)(smem + 50176);
  const int w2 = blockIdx.x, hh = blockIdx.y, b = blockIdx.z;
  const int w = w2 >> 1, qh = (w2 & 1) * 64;   // window, q-offset within window
  const int tid = threadIdx.x, wv = tid >> 6, lane = tid & 63;
  const int lr = lane & 15, lg = lane >> 4;
  const size_t qrow0 = (size_t)b * 2048 + (size_t)w * 128;   // first row of cur window

  // ---- stage V transposed VT[d][j] (64 rows x 512B), bias row, key mask ----
  for (int c = tid; c < 2048; c += 256) {
    int j = c >> 3, d0 = (c & 7) * 8;
    short8 vv;
    if (w == 0 && j < 128) {
#pragma unroll
      for (int t2 = 0; t2 < 8; t2++) vv[t2] = (short)0xBF80;   // pad V = -1.0
    } else {
      size_t gj = qrow0 + j - 128;
      vv = *(const short8*)(qkv + gj * 1536 + 1024 + hh * 64 + d0);
    }
#pragma unroll
    for (int t2 = 0; t2 < 8; t2++) {
      int d = d0 + t2;
      *(unsigned short*)(smem + 16384 + d * 512 + ((j * 2) ^ ((d & 7) << 4))) =
          (unsigned short)vv[t2];
    }
  }
  {
    tabh[tid] = tab[tid * 8 + hh];
    int j = tid;
    float kmv;
    if (w == 0 && j < 128) kmv = 0.f;                    // pad keys invalid
    else kmv = (x[qrow0 + j - 128] != 0) ? 1.f : 0.f;    // padding-token mask
    km[j] = kmv;
  }
  __syncthreads();

  // ---- sim^T = K @ Q^T : D[j][q], wave wv covers q = qh+wv*16+lr, all 256 j ----
  floatx4 sim[16];
#pragma unroll
  for (int nf = 0; nf < 16; nf++)
#pragma unroll
    for (int r = 0; r < 4; r++) sim[nf][r] = 0.f;
#pragma unroll
  for (int kk = 0; kk < 64; kk += 32) {
    size_t qr = qrow0 + qh + wv * 16 + lr;
    short8 bq = *(const short8*)(qkv + qr * 1536 + hh * 64 + kk + lg * 8);
#pragma unroll
    for (int nf = 0; nf < 16; nf++) {
      int j = nf * 16 + lr;                                        // K row (A-operand)
      size_t gj = (w == 0 && j < 128) ? qrow0 : (qrow0 + j - 128); // clamp: masked anyway
      short8 ak = *(const short8*)(qkv + gj * 1536 + 512 + hh * 64 + kk + lg * 8);
      sim[nf] = mfma_bf16(ak, bq, sim[nf]);   // A=K first -> D row = j, D col = q
    }
  }
  // ---- scale + bias + mask + softmax: thread owns q=qh+wv*16+lr, 64 j-values ----
  const int qi = qh + wv * 16 + lr;
  float mmax = -NEG_MAX;
#pragma unroll
  for (int nf = 0; nf < 16; nf++)
#pragma unroll
    for (int r = 0; r < 4; r++) {
      int jj = nf * 16 + lg * 4 + r;
      int di = 128 + qi - jj;
      if (di < 0) di = -di;
      float val = sim[nf][r] * 0.125f + tabh[di];
      bool causal = (nf < 8) ? (qi <= jj) : (jj - 128 <= qi);
      bool valid = causal && (km[jj] > 0.5f);
      float mv = valid ? val : -NEG_MAX;
      sim[nf][r] = mv;
      mmax = fmaxf(mmax, mv);
    }
  mmax = fmaxf(mmax, __shfl_xor(mmax, 16));
  mmax = fmaxf(mmax, __shfl_xor(mmax, 32));
  float lsum = 0.f;
#pragma unroll
  for (int nf = 0; nf < 16; nf++)
#pragma unroll
    for (int r = 0; r < 4; r++) {
      float e = __expf(sim[nf][r] - mmax);
      sim[nf][r] = e;            // unnormalized P; 1/l folded into epilogue
      lsum += e;
    }
  lsum += __shfl_xor(lsum, 16);
  lsum += __shfl_xor(lsum, 32);
  float inv_l = 1.f / lsum;      // valid at q = qh+wv*16+lr (all lg copies equal)

  floatx4 oacc[4];
#pragma unroll
  for (int nf = 0; nf < 4; nf++)
#pragma unroll
    for (int r = 0; r < 4; r++) oacc[nf][r] = 0.f;

  const int ql = wv * 16 + lr;   // local P row
#pragma unroll
  for (int t = 0; t < 2; t++) {
    // ---- write P tile t: 8x b64 packed (r 0..3 consecutive j) ----
#pragma unroll
    for (int nfl = 0; nfl < 8; nfl++) {
      int nf = t * 8 + nfl;
      unsigned int lo = (unsigned int)__bfloat16_as_ushort(__float2bfloat16(sim[nf][0])) |
                        ((unsigned int)__bfloat16_as_ushort(__float2bfloat16(sim[nf][1])) << 16);
      unsigned int hi = (unsigned int)__bfloat16_as_ushort(__float2bfloat16(sim[nf][2])) |
                        ((unsigned int)__bfloat16_as_ushort(__float2bfloat16(sim[nf][3])) << 16);
      uint2 pk; pk.x = lo; pk.y = hi;
      int bo = nfl * 32 + lg * 8;
      *(uint2*)(smem + ql * 256 + (bo ^ ((ql & 7) << 4))) = pk;
    }
    __syncthreads();             // P tile visible to all waves
    // ---- O += P_t @ V_t ----
#pragma unroll
    for (int kkl = 0; kkl < 128; kkl += 32) {
      int bo = kkl * 2 + lg * 16;
      short8 pa = *(const short8*)(smem + ql * 256 + (bo ^ ((ql & 7) << 4)));
      int vb = t * 256 + bo;     // VT byte col for jj = t*128 + kkl + lg*8
#pragma unroll
      for (int nf = 0; nf < 4; nf++) {
        int d = nf * 16 + lr;
        short8 bv = *(const short8*)(smem + 16384 + d * 512 + (vb ^ ((d & 7) << 4)));
        oacc[nf] = mfma_bf16(pa, bv, oacc[nf]);
      }
    }
    __syncthreads();             // PV reads done before next tile overwrites P
  }
  // ---- epilogue: scale rows by 1/l (rows q = lg*4+r owned by lane lr=lg*4+r) ----
  float invq[4];
#pragma unroll
  for (int r = 0; r < 4; r++) invq[r] = __shfl(inv_l, (lane & 48) | (lg * 4 + r));
#pragma unroll
  for (int nf = 0; nf < 4; nf++)
#pragma unroll
    for (int r = 0; r < 4; r++) {
      size_t n = qrow0 + qh + wv * 16 + lg * 4 + r;
      ob[n * 512 + hh * 64 + nf * 16 + lr] = __float2bfloat16(oacc[nf][r] * invq[r]);
    }
}

// ---------- host launcher ----------
extern "C" void kernel_launch(void* const* d_in, const int* in_sizes, int n_in,
                              void* d_out, int out_size, void* d_ws, size_t ws_size,
                              hipStream_t stream) {
  const int* x = (const int*)d_in[0];
  const float* emb = (const float*)d_in[1];
  const float* lag = (const float*)d_in[2];
  const float* lab = (const float*)d_in[3];
  const float* wqkv = (const float*)d_in[4];
  const float* wout = (const float*)d_in[5];
  const float* lfg = (const float*)d_in[6];
  const float* lfb = (const float*)d_in[7];
  const float* wff1 = (const float*)d_in[8];
  const float* wff2 = (const float*)d_in[9];
  const float* dw1 = (const float*)d_in[10];
  const float* db1 = (const float*)d_in[11];
  const float* dw2 = (const float*)d_in[12];
  const float* db2 = (const float*)d_in[13];
  const float* dw3 = (const float*)d_in[14];
  const float* db3 = (const float*)d_in[15];
  const float* log_g = (const float*)d_in[16];
  const float* log_b = (const float*)d_in[17];
  const float* wlog = (const float*)d_in[18];

  // ws layout (~140 MB; ob aliases z; FF a/gelu buffer aliases qkv in `big`)
  char* ws = (char*)d_ws;
  size_t off = 0;
  float* h = (float*)(ws + off); off += (size_t)16384 * 512 * 4;        //  33.6 MB
  bf16* z = (bf16*)(ws + off); off += (size_t)16384 * 512 * 2;          //  16.8 MB
  bf16* ob = z;                                                          //  alias
  bf16* big = (bf16*)(ws + off); off += (size_t)16384 * 1536 * 2;       //  50.3 MB
  bf16* qkvT = (bf16*)(ws + off); off += (size_t)6 * 1536 * 512 * 2;    //   9.4 MB
  bf16* woutT = (bf16*)(ws + off); off += (size_t)6 * 512 * 512 * 2;    //   3.1 MB
  bf16* ff1T = (bf16*)(ws + off); off += (size_t)6 * 2816 * 512 * 2;    //  17.3 MB
  bf16* ff2T = (bf16*)(ws + off); off += (size_t)6 * 512 * 1408 * 2;    //   8.7 MB
  bf16* logT = (bf16*)(ws + off); off += (size_t)512 * 512 * 2;         //   0.5 MB
  float* tab = (float*)(ws + off); off += (size_t)256 * 8 * 4;          //   8 KB

  auto cdiv = [](long t) { return (int)((t + 255) / 256); };

  prep_w<<<cdiv(6L * 1536 * 512), 256, 0, stream>>>(wqkv, qkvT, 512, 1536, 512, 1536, 6, 0);
  prep_w<<<cdiv(6L * 512 * 512), 256, 0, stream>>>(wout, woutT, 512, 512, 512, 512, 6, 0);
  prep_w<<<cdiv(6L * 2816 * 512), 256, 0, stream>>>(wff1, ff1T, 512, 2730, 512, 2816, 6, 1);
  prep_w<<<cdiv(6L * 512 * 1408), 256, 0, stream>>>(wff2, ff2T, 1365, 512, 1408, 512, 6, 0);
  prep_w<<<cdiv(512L * 512), 256, 0, stream>>>(wlog, logT, 512, 512, 512, 512, 1, 0);
  dpb_kernel<<<256, 256, 0, stream>>>(dw1, db1, dw2, db2, dw3, db3, tab);
  embed_kernel<<<32768, 256, 0, stream>>>(x, emb, h);

  for (int l = 0; l < 6; l++) {
    ln_kernel<<<4096, 256, 0, stream>>>(h, lag + l * 512, lab + l * 512, z);
    gemm_kernel<0><<<dim3(12, 128), 256, 0, stream>>>(z, qkvT + (size_t)l * 1536 * 512,
                                                      big, nullptr, 1536, 512);
    attn_kernel<<<dim3(32, 8, 8), 256, 0, stream>>>(big, x, tab, ob);
    gemm_kernel<1><<<dim3(4, 128), 256, 0, stream>>>(ob, woutT + (size_t)l * 512 * 512,
                                                     nullptr, h, 512, 512);
    ln_kernel<<<4096, 256, 0, stream>>>(h, lfg + l * 512, lfb + l * 512, z);
    // FF: a-half then g-half with fused GEGLU epilogue (in-place over `big`)
    gemm_kernel<0><<<dim3(11, 128), 256, 0, stream>>>(z, ff1T + (size_t)l * 2816 * 512,
                                                      big, nullptr, 1408, 512);
    gemm_kernel<2><<<dim3(11, 128), 256, 0, stream>>>(
        z, ff1T + (size_t)l * 2816 * 512 + (size_t)1408 * 512, big, nullptr, 1408, 512);
    gemm_kernel<1><<<dim3(4, 128), 256, 0, stream>>>(big, ff2T + (size_t)l * 512 * 1408,
                                                     nullptr, h, 512, 1408);
  }
  ln_kernel<<<4096, 256, 0, stream>>>(h, log_g, log_b, z);
  gemm_kernel<3><<<dim3(4, 128), 256, 0, stream>>>(z, logT, nullptr, (float*)d_out, 512, 512);
}